// Round 12
// baseline (150.305 us; speedup 1.0000x reference)
//
#include <hip/hip_runtime.h>

#define ND 1024
#define NNE (ND*ND)

typedef float f32x4 __attribute__((ext_vector_type(4)));
typedef int i32x4 __attribute__((ext_vector_type(4)));
typedef int i32x8 __attribute__((ext_vector_type(8)));

__device__ __forceinline__ void gload_lds16(const void* g, void* l) {
  __builtin_amdgcn_global_load_lds(
      (const __attribute__((address_space(1))) void*)g,
      (__attribute__((address_space(3))) void*)l, 16, 0, 0);
}

// ---- fused: zero phi row, convert x row -> fp8, phi[b,f,0] = x . lowpass ----
__global__ void convert_phi0_kernel(const float* __restrict__ x, const float* __restrict__ lp,
                                    unsigned char* __restrict__ x8, float* __restrict__ phi) {
  __shared__ float ws[4];
  int row = blockIdx.x;            // 256 rows
  int t   = threadIdx.x;           // 256 threads, one float4 each
  if (t >= 1 && t < 73) phi[row * 73 + t] = 0.f;   // replaces hipMemsetAsync
  float4 v = reinterpret_cast<const float4*>(x + (size_t)row * ND)[t];
  float4 l = reinterpret_cast<const float4*>(lp)[t];
  int pk = __builtin_amdgcn_cvt_pk_fp8_f32(v.x, v.y, 0, false);
  pk = __builtin_amdgcn_cvt_pk_fp8_f32(v.z, v.w, pk, true);
  reinterpret_cast<unsigned int*>(x8 + (size_t)row * ND)[t] = (unsigned int)pk;
  float s = v.x * l.x + v.y * l.y + v.z * l.z + v.w * l.w;
  #pragma unroll
  for (int off = 32; off; off >>= 1) s += __shfl_xor(s, off);
  if ((t & 63) == 0) ws[t >> 6] = s;
  __syncthreads();
  if (t == 0) phi[row * 73] = ws[0] + ws[1] + ws[2] + ws[3];
}

// ---- transpose+convert psi: fp8 out8[j][m][n] = psi[j][n][m] ----
__global__ void psi_transpose_kernel(const float* __restrict__ psi,
                                     unsigned char* __restrict__ out8) {
  __shared__ float t[32][33];
  int blk = blockIdx.x;
  int j  = blk >> 10;
  int tn = (blk >> 5) & 31;
  int tm = blk & 31;
  const float* src = psi + ((size_t)j << 20) + (size_t)(tn << 5) * ND + (tm << 5);
  int r  = threadIdx.x >> 3;
  int c4 = (threadIdx.x & 7) << 2;
  float4 v = *reinterpret_cast<const float4*>(src + (size_t)r * ND + c4);
  t[r][c4 + 0] = v.x; t[r][c4 + 1] = v.y; t[r][c4 + 2] = v.z; t[r][c4 + 3] = v.w;
  __syncthreads();
  float f0 = t[c4 + 0][r], f1 = t[c4 + 1][r], f2 = t[c4 + 2][r], f3 = t[c4 + 3][r];
  size_t base = ((size_t)j << 20) + (size_t)((tm << 5) + r) * ND + (tn << 5) + c4;
  int pk = __builtin_amdgcn_cvt_pk_fp8_f32(f0, f1, 0, false);
  pk = __builtin_amdgcn_cvt_pk_fp8_f32(f2, f3, pk, true);
  *reinterpret_cast<unsigned int*>(out8 + base) = (unsigned int)pk;
}

// ==== unified MX-fp8 scattering GEMM, m97/m148 structure ====
// 128x128 tile, 4 waves (64x64 each), BK=128 fp8, single-buffered 32 KB LDS,
// plain __syncthreads (compiler-inserted waitcnt), 2 blocks/CU for implicit
// cross-block overlap of barrier drains (m114 mechanism).

// one 32B fp8 fragment: two swizzled ds_read_b128 combined (k-order preserved)
__device__ __forceinline__ i32x8 dsr_frag8(const unsigned char* base, int r, int l4) {
  int s0 = l4 * 2;
  i32x4 lo = *reinterpret_cast<const i32x4*>(base + r * 128 + ((s0 ^ (r & 7)) << 4));
  i32x4 hi = *reinterpret_cast<const i32x4*>(base + r * 128 + (((s0 + 1) ^ (r & 7)) << 4));
  return __builtin_shufflevector(lo, hi, 0, 1, 2, 3, 4, 5, 6, 7);
}

// LAYER: 1 = x->S1 (stores S1 fp8, phi col 1+j), 2 = S1->phi cols 9..72
// MT_BITS: log2(# of 128-row M tiles): 1 for layer-1 (M=256), 4 for layer-2 (M=2048)
template<int LAYER, int MT_BITS>
__global__ __launch_bounds__(256, 2)
void gemm8(const unsigned char* __restrict__ A,
           const unsigned char* __restrict__ BT,
           const float* __restrict__ lowpass,
           unsigned char* __restrict__ Sout,
           float* __restrict__ phi) {
  __shared__ __align__(16) unsigned char As[128 * 128];  // 16 KB
  __shared__ __align__(16) unsigned char Bs[128 * 128];  // 16 KB

  const int tid  = threadIdx.x;
  const int lane = tid & 63;
  const int w    = tid >> 6;          // 4 waves: 2M x 2N
  const int wrow = w >> 1, wcol = w & 1;
  const int l15  = lane & 15, l4 = lane >> 4;

  // 1D grid, j = wg & 7: all blocks of one j land on one XCD (round-robin
  // dispatch) -> psi8[j] (1 MB) + S1 j-slice L2-resident per XCD.
  const int wg = blockIdx.x;
  const int j  = wg & 7;
  const int t  = wg >> 3;
  const int mtile = t & ((1 << MT_BITS) - 1);
  const int ntile = t >> MT_BITS;
  const int row0 = mtile * 128, n0 = ntile * 128;
  const unsigned char* Bj = BT + (size_t)j * NNE;

  f32x4 acc[4][4] = {};

  for (int k0 = 0; k0 < ND; k0 += 128) {
    __syncthreads();
    #pragma unroll
    for (int p = 0; p < 4; ++p) {
      int c = p * 256 + tid;
      int r = c >> 3;
      int s = (c & 7) ^ (r & 7);
      gload_lds16(A + (size_t)(row0 + r) * ND + k0 + (s << 4), As + c * 16);
    }
    #pragma unroll
    for (int p = 0; p < 4; ++p) {
      int c = p * 256 + tid;
      int r = c >> 3;
      int s = (c & 7) ^ (r & 7);
      gload_lds16(Bj + (size_t)(n0 + r) * ND + k0 + (s << 4), Bs + c * 16);
    }
    __syncthreads();

    i32x8 a[4], b[4];
    #pragma unroll
    for (int m = 0; m < 4; ++m)
      a[m] = dsr_frag8(As, wrow * 64 + m * 16 + l15, l4);
    #pragma unroll
    for (int n = 0; n < 4; ++n)
      b[n] = dsr_frag8(Bs, wcol * 64 + n * 16 + l15, l4);
    #pragma unroll
    for (int m = 0; m < 4; ++m)
      #pragma unroll
      for (int n = 0; n < 4; ++n)
        acc[m][n] = __builtin_amdgcn_mfma_scale_f32_16x16x128_f8f6f4(
            a[m], b[n], acc[m][n], 0, 0, 0, 0x7f7f7f7f, 0, 0x7f7f7f7f);
  }

  // epilogue: abs + lowpass dot + atomics (+ S1 fp8 store for LAYER 1)
  float lp[4];
  #pragma unroll
  for (int n = 0; n < 4; ++n)
    lp[n] = lowpass[n0 + wcol * 64 + n * 16 + l15];

  #pragma unroll
  for (int m = 0; m < 4; ++m) {
    #pragma unroll
    for (int r = 0; r < 4; ++r) {
      int rg = row0 + wrow * 64 + m * 16 + l4 * 4 + r;
      float psum = 0.f;
      #pragma unroll
      for (int n = 0; n < 4; ++n) {
        float v = fabsf(acc[m][n][r]);
        psum += v * lp[n];
        if (LAYER == 1) {
          int colg = n0 + wcol * 64 + n * 16 + l15;
          size_t si = ((size_t)((rg >> 4) * 8 + j) * 16 + (rg & 15)) * ND + colg;
          int pk = __builtin_amdgcn_cvt_pk_fp8_f32(v, v, 0, false);
          Sout[si] = (unsigned char)(pk & 0xff);
        }
      }
      psum += __shfl_xor(psum, 1);
      psum += __shfl_xor(psum, 2);
      psum += __shfl_xor(psum, 4);
      psum += __shfl_xor(psum, 8);
      if (l15 == 0) {
        int pidx;
        if (LAYER == 1) pidx = rg * 73 + 1 + j;
        else            pidx = ((rg >> 7) * 16 + (rg & 15)) * 73 + 9 + ((rg >> 4) & 7) * 8 + j;
        atomicAdd(&phi[pidx], psum);
      }
    }
  }
}

extern "C" void kernel_launch(void* const* d_in, const int* in_sizes, int n_in,
                              void* d_out, int out_size, void* d_ws, size_t ws_size,
                              hipStream_t stream) {
  (void)in_sizes; (void)n_in; (void)ws_size; (void)out_size;
  const float* x       = (const float*)d_in[0];
  const float* psi     = (const float*)d_in[1];
  const float* lowpass = (const float*)d_in[2];
  float* phi = (float*)d_out;

  unsigned char* x8    = (unsigned char*)d_ws;                        // 256 KB (fp8 x)
  unsigned char* psiT8 = (unsigned char*)((char*)d_ws + (1u << 20));  // 8 MB  (fp8 psi^T)
  unsigned char* S1f8  = (unsigned char*)((char*)d_ws + (10u << 20)); // 2 MB  (fp8 S1)

  convert_phi0_kernel<<<256, 256, 0, stream>>>(x, lowpass, x8, phi);
  psi_transpose_kernel<<<8192, 256, 0, stream>>>(psi, psiT8);

  // layer 1: M=256 -> 2 mtiles x 8 ntiles x 8 j = 128 blocks
  gemm8<1, 1><<<128, 256, 0, stream>>>(x8, psiT8, lowpass, S1f8, phi);

  // layer 2: M=2048 -> 16 mtiles x 8 ntiles x 8 j = 1024 blocks
  gemm8<2, 4><<<1024, 256, 0, stream>>>(S1f8, psiT8, lowpass, nullptr, phi);
}

// Round 13
// 69.970 us; speedup vs baseline: 2.1481x; 2.1481x over previous
//
#include <hip/hip_runtime.h>

#define ND 1024
#define NNE (ND*ND)

typedef __bf16 bf16x8 __attribute__((ext_vector_type(8)));
typedef float f32x4 __attribute__((ext_vector_type(4)));
typedef int i32x4 __attribute__((ext_vector_type(4)));
typedef int i32x8 __attribute__((ext_vector_type(8)));

__device__ __forceinline__ unsigned short f2bf(float f) {
  unsigned u = __float_as_uint(f);
  u += 0x7fffu + ((u >> 16) & 1u);
  return (unsigned short)(u >> 16);
}

__device__ __forceinline__ void gload_lds16(const void* g, void* l) {
  __builtin_amdgcn_global_load_lds(
      (const __attribute__((address_space(1))) void*)g,
      (__attribute__((address_space(3))) void*)l, 16, 0, 0);
}

// ---- fused: zero phi row, convert x row -> bf16, phi[b,f,0] = x . lowpass ----
__global__ void convert_phi0_kernel(const float* __restrict__ x, const float* __restrict__ lp,
                                    unsigned short* __restrict__ xb, float* __restrict__ phi) {
  __shared__ float ws[4];
  int row = blockIdx.x;
  int t   = threadIdx.x;
  if (t >= 1 && t < 73) phi[row * 73 + t] = 0.f;   // replaces hipMemsetAsync
  float4 v = reinterpret_cast<const float4*>(x + (size_t)row * ND)[t];
  float4 l = reinterpret_cast<const float4*>(lp)[t];
  ushort4 o;
  o.x = f2bf(v.x); o.y = f2bf(v.y); o.z = f2bf(v.z); o.w = f2bf(v.w);
  reinterpret_cast<ushort4*>(xb + (size_t)row * ND)[t] = o;
  float s = v.x * l.x + v.y * l.y + v.z * l.z + v.w * l.w;
  #pragma unroll
  for (int off = 32; off; off >>= 1) s += __shfl_xor(s, off);
  if ((t & 63) == 0) ws[t >> 6] = s;
  __syncthreads();
  if (t == 0) phi[row * 73] = ws[0] + ws[1] + ws[2] + ws[3];
}

// ---- transpose+convert psi: bf16 out[j][m][n] AND fp8 out8[j][m][n] = psi[j][n][m] ----
__global__ void psi_transpose_kernel(const float* __restrict__ psi,
                                     unsigned short* __restrict__ out,
                                     unsigned char* __restrict__ out8) {
  __shared__ float t[32][33];
  int blk = blockIdx.x;
  int j  = blk >> 10;
  int tn = (blk >> 5) & 31;
  int tm = blk & 31;
  const float* src = psi + ((size_t)j << 20) + (size_t)(tn << 5) * ND + (tm << 5);
  int r  = threadIdx.x >> 3;
  int c4 = (threadIdx.x & 7) << 2;
  float4 v = *reinterpret_cast<const float4*>(src + (size_t)r * ND + c4);
  t[r][c4 + 0] = v.x; t[r][c4 + 1] = v.y; t[r][c4 + 2] = v.z; t[r][c4 + 3] = v.w;
  __syncthreads();
  float f0 = t[c4 + 0][r], f1 = t[c4 + 1][r], f2 = t[c4 + 2][r], f3 = t[c4 + 3][r];
  ushort4 o;
  o.x = f2bf(f0); o.y = f2bf(f1); o.z = f2bf(f2); o.w = f2bf(f3);
  size_t base = ((size_t)j << 20) + (size_t)((tm << 5) + r) * ND + (tn << 5) + c4;
  *reinterpret_cast<ushort4*>(out + base) = o;
  int pk = __builtin_amdgcn_cvt_pk_fp8_f32(f0, f1, 0, false);
  pk = __builtin_amdgcn_cvt_pk_fp8_f32(f2, f3, pk, true);
  *reinterpret_cast<unsigned int*>(out8 + base) = (unsigned int)pk;
}

// ==== layer-1 GEMM (bf16, verified round-0 structure; stores S1 as fp8) ====
template<int BM, int BN>
__global__ __launch_bounds__(256)
void gemm_scat(const unsigned short* __restrict__ A,
               const unsigned short* __restrict__ BT,
               const float* __restrict__ lowpass,
               unsigned char* __restrict__ Sout,
               float* __restrict__ phi) {
  constexpr int BK = 64;
  constexpr int WM = BM / 2, WN = BN / 2;
  constexpr int MF = WM / 16, NF = WN / 16;

  __shared__ __align__(16) unsigned short Asm[BM * BK];
  __shared__ __align__(16) unsigned short Bsm[BN * BK];

  const int tid  = threadIdx.x;
  const int lane = tid & 63;
  const int w    = tid >> 6;
  const int wrow = w >> 1, wcol = w & 1;

  const int j    = blockIdx.z;
  const int row0 = blockIdx.y * BM;
  const int n0   = blockIdx.x * BN;

  const unsigned short* Bj = BT + (size_t)j * NNE;

  f32x4 acc[MF][NF] = {};

  constexpr int ACH = BM * 8;
  constexpr int BCH = BN * 8;

  for (int k0 = 0; k0 < ND; k0 += BK) {
    __syncthreads();
    #pragma unroll
    for (int p = 0; p < ACH / 256; ++p) {
      int c = p * 256 + tid;
      int r = c >> 3;
      int s = (c & 7) ^ (r & 7);
      gload_lds16(A + (size_t)(row0 + r) * ND + k0 + s * 8, Asm + c * 8);
    }
    #pragma unroll
    for (int p = 0; p < BCH / 256; ++p) {
      int c = p * 256 + tid;
      int r = c >> 3;
      int s = (c & 7) ^ (r & 7);
      gload_lds16(Bj + (size_t)(n0 + r) * ND + k0 + s * 8, Bsm + c * 8);
    }
    __syncthreads();

    #pragma unroll
    for (int kk = 0; kk < 2; ++kk) {
      bf16x8 a[MF], b[NF];
      int srd = kk * 4 + (lane >> 4);
      #pragma unroll
      for (int m = 0; m < MF; ++m) {
        int r = wrow * WM + m * 16 + (lane & 15);
        a[m] = *reinterpret_cast<const bf16x8*>(&Asm[r * 64 + ((srd ^ (r & 7)) * 8)]);
      }
      #pragma unroll
      for (int n = 0; n < NF; ++n) {
        int r = wcol * WN + n * 16 + (lane & 15);
        b[n] = *reinterpret_cast<const bf16x8*>(&Bsm[r * 64 + ((srd ^ (r & 7)) * 8)]);
      }
      #pragma unroll
      for (int m = 0; m < MF; ++m)
        #pragma unroll
        for (int n = 0; n < NF; ++n)
          acc[m][n] = __builtin_amdgcn_mfma_f32_16x16x32_bf16(a[m], b[n], acc[m][n], 0, 0, 0);
    }
  }

  float lp[NF];
  #pragma unroll
  for (int n = 0; n < NF; ++n)
    lp[n] = lowpass[n0 + wcol * WN + n * 16 + (lane & 15)];

  #pragma unroll
  for (int m = 0; m < MF; ++m) {
    #pragma unroll
    for (int r = 0; r < 4; ++r) {
      int rg = row0 + wrow * WM + m * 16 + (lane >> 4) * 4 + r;
      float psum = 0.f;
      #pragma unroll
      for (int n = 0; n < NF; ++n) {
        float v = fabsf(acc[m][n][r]);
        psum += v * lp[n];
        int colg = n0 + wcol * WN + n * 16 + (lane & 15);
        size_t si = ((size_t)((rg >> 4) * 8 + j) * 16 + (rg & 15)) * ND + colg;
        int pk = __builtin_amdgcn_cvt_pk_fp8_f32(v, v, 0, false);
        Sout[si] = (unsigned char)(pk & 0xff);
      }
      psum += __shfl_xor(psum, 1);
      psum += __shfl_xor(psum, 2);
      psum += __shfl_xor(psum, 4);
      psum += __shfl_xor(psum, 8);
      if ((lane & 15) == 0) {
        int pidx = rg * 73 + 1 + j;
        atomicAdd(&phi[pidx], psum);
      }
    }
  }
}

// ==== layer-2: MX-fp8, m97/m148 structure. 512 blocks (= exactly 2/CU, all
//      resident => j = wg&7 stays XCD-pure), 2 output tiles of 128x128 per
//      block, BK=128, single-buffered 32 KB LDS, plain __syncthreads ====

// one 32B fp8 fragment: two swizzled ds_read_b128 combined (k-order preserved)
__device__ __forceinline__ i32x8 dsr_frag8(const unsigned char* base, int r, int l4) {
  int s0 = l4 * 2;
  i32x4 lo = *reinterpret_cast<const i32x4*>(base + r * 128 + ((s0 ^ (r & 7)) << 4));
  i32x4 hi = *reinterpret_cast<const i32x4*>(base + r * 128 + (((s0 + 1) ^ (r & 7)) << 4));
  return __builtin_shufflevector(lo, hi, 0, 1, 2, 3, 4, 5, 6, 7);
}

__global__ __launch_bounds__(256, 2)
void gemm8_l2(const unsigned char* __restrict__ A,
              const unsigned char* __restrict__ BT,
              const float* __restrict__ lowpass,
              float* __restrict__ phi) {
  __shared__ __align__(16) unsigned char As[128 * 128];  // 16 KB
  __shared__ __align__(16) unsigned char Bs[128 * 128];  // 16 KB

  const int tid  = threadIdx.x;
  const int lane = tid & 63;
  const int w    = tid >> 6;          // 4 waves: 2M x 2N
  const int wrow = w >> 1, wcol = w & 1;
  const int l15  = lane & 15, l4 = lane >> 4;

  const int wg  = blockIdx.x;
  const int j   = wg & 7;             // XCD-pure (512 blocks all resident)
  const int idx = wg >> 3;            // 0..63
  const unsigned char* Bj = BT + (size_t)j * NNE;

  #pragma unroll 1
  for (int tt = 0; tt < 2; ++tt) {
    const int t = idx + tt * 64;      // 0..127
    const int mtile = t & 15, ntile = t >> 4;
    const int row0 = mtile * 128, n0 = ntile * 128;

    f32x4 acc[4][4] = {};

    #pragma unroll 1
    for (int k0 = 0; k0 < ND; k0 += 128) {
      __syncthreads();
      #pragma unroll
      for (int p = 0; p < 4; ++p) {
        int c = p * 256 + tid;
        int r = c >> 3;
        int s = (c & 7) ^ (r & 7);
        gload_lds16(A + (size_t)(row0 + r) * ND + k0 + (s << 4), As + c * 16);
      }
      #pragma unroll
      for (int p = 0; p < 4; ++p) {
        int c = p * 256 + tid;
        int r = c >> 3;
        int s = (c & 7) ^ (r & 7);
        gload_lds16(Bj + (size_t)(n0 + r) * ND + k0 + (s << 4), Bs + c * 16);
      }
      __syncthreads();

      i32x8 a[4], b[4];
      #pragma unroll
      for (int m = 0; m < 4; ++m)
        a[m] = dsr_frag8(As, wrow * 64 + m * 16 + l15, l4);
      #pragma unroll
      for (int n = 0; n < 4; ++n)
        b[n] = dsr_frag8(Bs, wcol * 64 + n * 16 + l15, l4);
      #pragma unroll
      for (int m = 0; m < 4; ++m)
        #pragma unroll
        for (int n = 0; n < 4; ++n)
          acc[m][n] = __builtin_amdgcn_mfma_scale_f32_16x16x128_f8f6f4(
              a[m], b[n], acc[m][n], 0, 0, 0, 0x7f7f7f7f, 0, 0x7f7f7f7f);
    }

    // epilogue: abs + lowpass dot + atomics into phi[...,9+k*8+j]
    float lp[4];
    #pragma unroll
    for (int n = 0; n < 4; ++n)
      lp[n] = lowpass[n0 + wcol * 64 + n * 16 + l15];

    #pragma unroll
    for (int m = 0; m < 4; ++m) {
      #pragma unroll
      for (int r = 0; r < 4; ++r) {
        int rg = row0 + wrow * 64 + m * 16 + l4 * 4 + r;
        float psum = 0.f;
        #pragma unroll
        for (int n = 0; n < 4; ++n)
          psum += fabsf(acc[m][n][r]) * lp[n];
        psum += __shfl_xor(psum, 1);
        psum += __shfl_xor(psum, 2);
        psum += __shfl_xor(psum, 4);
        psum += __shfl_xor(psum, 8);
        if (l15 == 0) {
          int pidx = ((rg >> 7) * 16 + (rg & 15)) * 73 + 9 + ((rg >> 4) & 7) * 8 + j;
          atomicAdd(&phi[pidx], psum);
        }
      }
    }
  }
}

extern "C" void kernel_launch(void* const* d_in, const int* in_sizes, int n_in,
                              void* d_out, int out_size, void* d_ws, size_t ws_size,
                              hipStream_t stream) {
  (void)in_sizes; (void)n_in; (void)ws_size; (void)out_size;
  const float* x       = (const float*)d_in[0];
  const float* psi     = (const float*)d_in[1];
  const float* lowpass = (const float*)d_in[2];
  float* phi = (float*)d_out;

  unsigned short* xb    = (unsigned short*)d_ws;                        // 512 KB (bf16 x)
  unsigned short* psiT  = (unsigned short*)((char*)d_ws + (1u  << 20)); // 16 MB  (bf16 psi^T)
  unsigned char*  S1f8  = (unsigned char*) ((char*)d_ws + (17u << 20)); // 2 MB   (fp8 S1)
  unsigned char*  psiT8 = (unsigned char*) ((char*)d_ws + (19u << 20)); // 8 MB   (fp8 psi^T)

  convert_phi0_kernel<<<256, 256, 0, stream>>>(x, lowpass, xb, phi);
  psi_transpose_kernel<<<8192, 256, 0, stream>>>(psi, psiT, psiT8);

  // layer 1: bf16 MFMA, M=256, tiles 64x128 -> grid (8, 4, 8); stores S1 as fp8
  gemm_scat<64, 128><<<dim3(8, 4, 8), 256, 0, stream>>>(xb, psiT, lowpass, S1f8, phi);

  // layer 2: MX-fp8 128x128 tiles, 512 blocks (2/CU, all resident), 2 tiles/block
  gemm8_l2<<<512, 256, 0, stream>>>(S1f8, psiT8, lowpass, phi);
}

// Round 14
// 64.626 us; speedup vs baseline: 2.3258x; 1.0827x over previous
//
#include <hip/hip_runtime.h>

#define ND 1024
#define NNE (ND*ND)

typedef float f32x4 __attribute__((ext_vector_type(4)));
typedef int i32x4 __attribute__((ext_vector_type(4)));
typedef int i32x8 __attribute__((ext_vector_type(8)));

__device__ __forceinline__ void gload_lds16(const void* g, void* l) {
  __builtin_amdgcn_global_load_lds(
      (const __attribute__((address_space(1))) void*)g,
      (__attribute__((address_space(3))) void*)l, 16, 0, 0);
}

// ---- fused: zero phi row, convert x row -> fp8, phi[b,f,0] = x . lowpass ----
__global__ void convert_phi0_kernel(const float* __restrict__ x, const float* __restrict__ lp,
                                    unsigned char* __restrict__ x8, float* __restrict__ phi) {
  __shared__ float ws[4];
  int row = blockIdx.x;            // 256 rows
  int t   = threadIdx.x;           // 256 threads, one float4 each
  if (t >= 1 && t < 73) phi[row * 73 + t] = 0.f;   // replaces hipMemsetAsync
  float4 v = reinterpret_cast<const float4*>(x + (size_t)row * ND)[t];
  float4 l = reinterpret_cast<const float4*>(lp)[t];
  int pk = __builtin_amdgcn_cvt_pk_fp8_f32(v.x, v.y, 0, false);
  pk = __builtin_amdgcn_cvt_pk_fp8_f32(v.z, v.w, pk, true);
  reinterpret_cast<unsigned int*>(x8 + (size_t)row * ND)[t] = (unsigned int)pk;
  float s = v.x * l.x + v.y * l.y + v.z * l.z + v.w * l.w;
  #pragma unroll
  for (int off = 32; off; off >>= 1) s += __shfl_xor(s, off);
  if ((t & 63) == 0) ws[t >> 6] = s;
  __syncthreads();
  if (t == 0) phi[row * 73] = ws[0] + ws[1] + ws[2] + ws[3];
}

// ---- transpose+convert psi: fp8 out8[j][m][n] = psi[j][n][m] ----
__global__ void psi_transpose_kernel(const float* __restrict__ psi,
                                     unsigned char* __restrict__ out8) {
  __shared__ float t[32][33];
  int blk = blockIdx.x;
  int j  = blk >> 10;
  int tn = (blk >> 5) & 31;
  int tm = blk & 31;
  const float* src = psi + ((size_t)j << 20) + (size_t)(tn << 5) * ND + (tm << 5);
  int r  = threadIdx.x >> 3;
  int c4 = (threadIdx.x & 7) << 2;
  float4 v = *reinterpret_cast<const float4*>(src + (size_t)r * ND + c4);
  t[r][c4 + 0] = v.x; t[r][c4 + 1] = v.y; t[r][c4 + 2] = v.z; t[r][c4 + 3] = v.w;
  __syncthreads();
  float f0 = t[c4 + 0][r], f1 = t[c4 + 1][r], f2 = t[c4 + 2][r], f3 = t[c4 + 3][r];
  size_t base = ((size_t)j << 20) + (size_t)((tm << 5) + r) * ND + (tn << 5) + c4;
  int pk = __builtin_amdgcn_cvt_pk_fp8_f32(f0, f1, 0, false);
  pk = __builtin_amdgcn_cvt_pk_fp8_f32(f2, f3, pk, true);
  *reinterpret_cast<unsigned int*>(out8 + base) = (unsigned int)pk;
}

// one 32B fp8 fragment: two swizzled ds_read_b128 combined (k-order preserved)
__device__ __forceinline__ i32x8 dsr_frag8(const unsigned char* base, int r, int l4) {
  int s0 = l4 * 2;
  i32x4 lo = *reinterpret_cast<const i32x4*>(base + r * 128 + ((s0 ^ (r & 7)) << 4));
  i32x4 hi = *reinterpret_cast<const i32x4*>(base + r * 128 + (((s0 + 1) ^ (r & 7)) << 4));
  return __builtin_shufflevector(lo, hi, 0, 1, 2, 3, 4, 5, 6, 7);
}

// ==== layer-1: MX-fp8 m97 structure (validated round 12) ====
// 128x128 tile, 4 waves (64x64 each), BK=128, single-buffered 32 KB LDS.
// M=256 -> 2 mtiles x 8 ntiles x 8 j = 128 blocks (all resident, j-pure).
__global__ __launch_bounds__(256, 2)
void gemm8_l1(const unsigned char* __restrict__ A,
              const unsigned char* __restrict__ BT,
              const float* __restrict__ lowpass,
              unsigned char* __restrict__ Sout,
              float* __restrict__ phi) {
  __shared__ __align__(16) unsigned char As[128 * 128];
  __shared__ __align__(16) unsigned char Bs[128 * 128];

  const int tid  = threadIdx.x;
  const int lane = tid & 63;
  const int w    = tid >> 6;          // 4 waves: 2M x 2N
  const int wrow = w >> 1, wcol = w & 1;
  const int l15  = lane & 15, l4 = lane >> 4;

  const int wg = blockIdx.x;
  const int j  = wg & 7;
  const int t  = wg >> 3;             // 0..15
  const int mtile = t & 1, ntile = t >> 1;
  const int row0 = mtile * 128, n0 = ntile * 128;
  const unsigned char* Bj = BT + (size_t)j * NNE;

  f32x4 acc[4][4] = {};

  #pragma unroll 1
  for (int k0 = 0; k0 < ND; k0 += 128) {
    __syncthreads();
    #pragma unroll
    for (int p = 0; p < 4; ++p) {
      int c = p * 256 + tid;
      int r = c >> 3;
      int s = (c & 7) ^ (r & 7);
      gload_lds16(A + (size_t)(row0 + r) * ND + k0 + (s << 4), As + c * 16);
    }
    #pragma unroll
    for (int p = 0; p < 4; ++p) {
      int c = p * 256 + tid;
      int r = c >> 3;
      int s = (c & 7) ^ (r & 7);
      gload_lds16(Bj + (size_t)(n0 + r) * ND + k0 + (s << 4), Bs + c * 16);
    }
    __syncthreads();

    i32x8 a[4], b[4];
    #pragma unroll
    for (int m = 0; m < 4; ++m)
      a[m] = dsr_frag8(As, wrow * 64 + m * 16 + l15, l4);
    #pragma unroll
    for (int n = 0; n < 4; ++n)
      b[n] = dsr_frag8(Bs, wcol * 64 + n * 16 + l15, l4);
    #pragma unroll
    for (int m = 0; m < 4; ++m)
      #pragma unroll
      for (int n = 0; n < 4; ++n)
        acc[m][n] = __builtin_amdgcn_mfma_scale_f32_16x16x128_f8f6f4(
            a[m], b[n], acc[m][n], 0, 0, 0, 0x7f7f7f7f, 0, 0x7f7f7f7f);
  }

  // epilogue: abs + lowpass dot + S1 fp8 store + phi col 1+j
  float lp[4];
  #pragma unroll
  for (int n = 0; n < 4; ++n)
    lp[n] = lowpass[n0 + wcol * 64 + n * 16 + l15];

  #pragma unroll
  for (int m = 0; m < 4; ++m) {
    #pragma unroll
    for (int r = 0; r < 4; ++r) {
      int rg = row0 + wrow * 64 + m * 16 + l4 * 4 + r;
      float psum = 0.f;
      #pragma unroll
      for (int n = 0; n < 4; ++n) {
        float v = fabsf(acc[m][n][r]);
        psum += v * lp[n];
        int colg = n0 + wcol * 64 + n * 16 + l15;
        size_t si = ((size_t)((rg >> 4) * 8 + j) * 16 + (rg & 15)) * ND + colg;
        int pk = __builtin_amdgcn_cvt_pk_fp8_f32(v, v, 0, false);
        Sout[si] = (unsigned char)(pk & 0xff);
      }
      psum += __shfl_xor(psum, 1);
      psum += __shfl_xor(psum, 2);
      psum += __shfl_xor(psum, 4);
      psum += __shfl_xor(psum, 8);
      if (l15 == 0) {
        int pidx = rg * 73 + 1 + j;
        atomicAdd(&phi[pidx], psum);
      }
    }
  }
}

// ==== layer-2: MX-fp8, round-13 structure (byte-identical; best measured) ====
// 512 blocks (= exactly 2/CU, all resident => j = wg&7 stays XCD-pure),
// 2 output tiles of 128x128 per block, BK=128, single-buffered 32 KB LDS.
__global__ __launch_bounds__(256, 2)
void gemm8_l2(const unsigned char* __restrict__ A,
              const unsigned char* __restrict__ BT,
              const float* __restrict__ lowpass,
              float* __restrict__ phi) {
  __shared__ __align__(16) unsigned char As[128 * 128];
  __shared__ __align__(16) unsigned char Bs[128 * 128];

  const int tid  = threadIdx.x;
  const int lane = tid & 63;
  const int w    = tid >> 6;          // 4 waves: 2M x 2N
  const int wrow = w >> 1, wcol = w & 1;
  const int l15  = lane & 15, l4 = lane >> 4;

  const int wg  = blockIdx.x;
  const int j   = wg & 7;             // XCD-pure (512 blocks all resident)
  const int idx = wg >> 3;            // 0..63
  const unsigned char* Bj = BT + (size_t)j * NNE;

  #pragma unroll 1
  for (int tt = 0; tt < 2; ++tt) {
    const int t = idx + tt * 64;      // 0..127
    const int mtile = t & 15, ntile = t >> 4;
    const int row0 = mtile * 128, n0 = ntile * 128;

    f32x4 acc[4][4] = {};

    #pragma unroll 1
    for (int k0 = 0; k0 < ND; k0 += 128) {
      __syncthreads();
      #pragma unroll
      for (int p = 0; p < 4; ++p) {
        int c = p * 256 + tid;
        int r = c >> 3;
        int s = (c & 7) ^ (r & 7);
        gload_lds16(A + (size_t)(row0 + r) * ND + k0 + (s << 4), As + c * 16);
      }
      #pragma unroll
      for (int p = 0; p < 4; ++p) {
        int c = p * 256 + tid;
        int r = c >> 3;
        int s = (c & 7) ^ (r & 7);
        gload_lds16(Bj + (size_t)(n0 + r) * ND + k0 + (s << 4), Bs + c * 16);
      }
      __syncthreads();

      i32x8 a[4], b[4];
      #pragma unroll
      for (int m = 0; m < 4; ++m)
        a[m] = dsr_frag8(As, wrow * 64 + m * 16 + l15, l4);
      #pragma unroll
      for (int n = 0; n < 4; ++n)
        b[n] = dsr_frag8(Bs, wcol * 64 + n * 16 + l15, l4);
      #pragma unroll
      for (int m = 0; m < 4; ++m)
        #pragma unroll
        for (int n = 0; n < 4; ++n)
          acc[m][n] = __builtin_amdgcn_mfma_scale_f32_16x16x128_f8f6f4(
              a[m], b[n], acc[m][n], 0, 0, 0, 0x7f7f7f7f, 0, 0x7f7f7f7f);
    }

    // epilogue: abs + lowpass dot + atomics into phi[...,9+k*8+j]
    float lp[4];
    #pragma unroll
    for (int n = 0; n < 4; ++n)
      lp[n] = lowpass[n0 + wcol * 64 + n * 16 + l15];

    #pragma unroll
    for (int m = 0; m < 4; ++m) {
      #pragma unroll
      for (int r = 0; r < 4; ++r) {
        int rg = row0 + wrow * 64 + m * 16 + l4 * 4 + r;
        float psum = 0.f;
        #pragma unroll
        for (int n = 0; n < 4; ++n)
          psum += fabsf(acc[m][n][r]) * lp[n];
        psum += __shfl_xor(psum, 1);
        psum += __shfl_xor(psum, 2);
        psum += __shfl_xor(psum, 4);
        psum += __shfl_xor(psum, 8);
        if (l15 == 0) {
          int pidx = ((rg >> 7) * 16 + (rg & 15)) * 73 + 9 + ((rg >> 4) & 7) * 8 + j;
          atomicAdd(&phi[pidx], psum);
        }
      }
    }
  }
}

extern "C" void kernel_launch(void* const* d_in, const int* in_sizes, int n_in,
                              void* d_out, int out_size, void* d_ws, size_t ws_size,
                              hipStream_t stream) {
  (void)in_sizes; (void)n_in; (void)ws_size; (void)out_size;
  const float* x       = (const float*)d_in[0];
  const float* psi     = (const float*)d_in[1];
  const float* lowpass = (const float*)d_in[2];
  float* phi = (float*)d_out;

  unsigned char* x8    = (unsigned char*)d_ws;                        // 256 KB (fp8 x)
  unsigned char* psiT8 = (unsigned char*)((char*)d_ws + (1u << 20));  // 8 MB  (fp8 psi^T)
  unsigned char* S1f8  = (unsigned char*)((char*)d_ws + (10u << 20)); // 2 MB  (fp8 S1)

  convert_phi0_kernel<<<256, 256, 0, stream>>>(x, lowpass, x8, phi);
  psi_transpose_kernel<<<8192, 256, 0, stream>>>(psi, psiT8);

  // layer 1: M=256 -> 128 blocks (all resident, j-pure), stores S1 fp8
  gemm8_l1<<<128, 256, 0, stream>>>(x8, psiT8, lowpass, S1f8, phi);

  // layer 2: 512 blocks (2/CU, all resident), 2 tiles/block
  gemm8_l2<<<512, 256, 0, stream>>>(S1f8, psiT8, lowpass, phi);
}

// Round 15
// 64.369 us; speedup vs baseline: 2.3350x; 1.0040x over previous
//
#include <hip/hip_runtime.h>

#define ND 1024
#define NNE (ND*ND)

typedef float f32x4 __attribute__((ext_vector_type(4)));
typedef int i32x4 __attribute__((ext_vector_type(4)));
typedef int i32x8 __attribute__((ext_vector_type(8)));

__device__ __forceinline__ void gload_lds16(const void* g, void* l) {
  __builtin_amdgcn_global_load_lds(
      (const __attribute__((address_space(1))) void*)g,
      (__attribute__((address_space(3))) void*)l, 16, 0, 0);
}

// ==== fused prep: 512 transpose blocks + 256 convert/phi0 blocks ====
// transpose: out8[j][m][n] = fp8(psi[j][n][m]), 128x128 tiles, full-line writes
// convert:   x8 = fp8(x), phi[row][0] = x.lowpass, phi[row][1..72] = 0
__global__ __launch_bounds__(256)
void prep_kernel(const float* __restrict__ psi, unsigned char* __restrict__ out8,
                 const float* __restrict__ x, const float* __restrict__ lp,
                 unsigned char* __restrict__ x8, float* __restrict__ phi) {
  __shared__ __align__(16) unsigned char T[128 * 144];  // 18 KB, 16B-aligned rows
  __shared__ float ws[4];
  const int blk = blockIdx.x;
  const int tid = threadIdx.x;

  if (blk >= 512) {
    // ---- convert path ----
    int row = blk - 512;
    if (tid >= 1 && tid < 73) phi[row * 73 + tid] = 0.f;
    float4 v = reinterpret_cast<const float4*>(x + (size_t)row * ND)[tid];
    float4 l = reinterpret_cast<const float4*>(lp)[tid];
    int pk = __builtin_amdgcn_cvt_pk_fp8_f32(v.x, v.y, 0, false);
    pk = __builtin_amdgcn_cvt_pk_fp8_f32(v.z, v.w, pk, true);
    reinterpret_cast<unsigned int*>(x8 + (size_t)row * ND)[tid] = (unsigned int)pk;
    float s = v.x * l.x + v.y * l.y + v.z * l.z + v.w * l.w;
    #pragma unroll
    for (int off = 32; off; off >>= 1) s += __shfl_xor(s, off);
    if ((tid & 63) == 0) ws[tid >> 6] = s;
    __syncthreads();
    if (tid == 0) phi[row * 73] = ws[0] + ws[1] + ws[2] + ws[3];
    return;
  }

  // ---- transpose path: j = blk>>6, tile (tn, tm) of 128x128 ----
  const int j  = blk >> 6;
  const int t6 = blk & 63;
  const int tn = t6 >> 3, tm = t6 & 7;
  const int n0 = tn * 128, m0 = tm * 128;
  const float* src = psi + ((size_t)j << 20) + (size_t)n0 * ND + m0;

  const int rgrp = tid >> 5;           // 0..7 (row within iter-group)
  const int c4   = (tid & 31) << 2;    // 0..124 (col, 4-wide)
  #pragma unroll
  for (int it = 0; it < 16; ++it) {
    int nl = it * 8 + rgrp;
    float4 v = *reinterpret_cast<const float4*>(src + (size_t)nl * ND + c4);
    int p01 = __builtin_amdgcn_cvt_pk_fp8_f32(v.x, v.y, 0, false);
    int p23 = __builtin_amdgcn_cvt_pk_fp8_f32(v.z, v.w, 0, false);
    T[(c4 + 0) * 144 + nl] = (unsigned char)(p01 & 0xff);
    T[(c4 + 1) * 144 + nl] = (unsigned char)((p01 >> 8) & 0xff);
    T[(c4 + 2) * 144 + nl] = (unsigned char)(p23 & 0xff);
    T[(c4 + 3) * 144 + nl] = (unsigned char)((p23 >> 8) & 0xff);
  }
  __syncthreads();

  unsigned char* dst = out8 + ((size_t)j << 20) + (size_t)m0 * ND + n0;
  const int mrow = tid >> 3;           // 0..31
  const int ch   = (tid & 7) << 4;     // 0..112 (16B chunk)
  #pragma unroll
  for (int it = 0; it < 4; ++it) {
    int ml = it * 32 + mrow;
    uint4 v = *reinterpret_cast<const uint4*>(&T[ml * 144 + ch]);
    *reinterpret_cast<uint4*>(dst + (size_t)ml * ND + ch) = v;
  }
}

// one 32B fp8 fragment: two swizzled ds_read_b128 combined (k-order preserved)
__device__ __forceinline__ i32x8 dsr_frag8(const unsigned char* base, int r, int l4) {
  int s0 = l4 * 2;
  i32x4 lo = *reinterpret_cast<const i32x4*>(base + r * 128 + ((s0 ^ (r & 7)) << 4));
  i32x4 hi = *reinterpret_cast<const i32x4*>(base + r * 128 + (((s0 + 1) ^ (r & 7)) << 4));
  return __builtin_shufflevector(lo, hi, 0, 1, 2, 3, 4, 5, 6, 7);
}

// ==== layer-1: MX-fp8 m97 structure (validated rounds 12/14) ====
__global__ __launch_bounds__(256, 2)
void gemm8_l1(const unsigned char* __restrict__ A,
              const unsigned char* __restrict__ BT,
              const float* __restrict__ lowpass,
              unsigned char* __restrict__ Sout,
              float* __restrict__ phi) {
  __shared__ __align__(16) unsigned char As[128 * 128];
  __shared__ __align__(16) unsigned char Bs[128 * 128];

  const int tid  = threadIdx.x;
  const int lane = tid & 63;
  const int w    = tid >> 6;          // 4 waves: 2M x 2N
  const int wrow = w >> 1, wcol = w & 1;
  const int l15  = lane & 15, l4 = lane >> 4;

  const int wg = blockIdx.x;
  const int j  = wg & 7;
  const int t  = wg >> 3;             // 0..15
  const int mtile = t & 1, ntile = t >> 1;
  const int row0 = mtile * 128, n0 = ntile * 128;
  const unsigned char* Bj = BT + (size_t)j * NNE;

  f32x4 acc[4][4] = {};

  #pragma unroll 1
  for (int k0 = 0; k0 < ND; k0 += 128) {
    __syncthreads();
    #pragma unroll
    for (int p = 0; p < 4; ++p) {
      int c = p * 256 + tid;
      int r = c >> 3;
      int s = (c & 7) ^ (r & 7);
      gload_lds16(A + (size_t)(row0 + r) * ND + k0 + (s << 4), As + c * 16);
    }
    #pragma unroll
    for (int p = 0; p < 4; ++p) {
      int c = p * 256 + tid;
      int r = c >> 3;
      int s = (c & 7) ^ (r & 7);
      gload_lds16(Bj + (size_t)(n0 + r) * ND + k0 + (s << 4), Bs + c * 16);
    }
    __syncthreads();

    i32x8 a[4], b[4];
    #pragma unroll
    for (int m = 0; m < 4; ++m)
      a[m] = dsr_frag8(As, wrow * 64 + m * 16 + l15, l4);
    #pragma unroll
    for (int n = 0; n < 4; ++n)
      b[n] = dsr_frag8(Bs, wcol * 64 + n * 16 + l15, l4);
    #pragma unroll
    for (int m = 0; m < 4; ++m)
      #pragma unroll
      for (int n = 0; n < 4; ++n)
        acc[m][n] = __builtin_amdgcn_mfma_scale_f32_16x16x128_f8f6f4(
            a[m], b[n], acc[m][n], 0, 0, 0, 0x7f7f7f7f, 0, 0x7f7f7f7f);
  }

  float lp[4];
  #pragma unroll
  for (int n = 0; n < 4; ++n)
    lp[n] = lowpass[n0 + wcol * 64 + n * 16 + l15];

  #pragma unroll
  for (int m = 0; m < 4; ++m) {
    #pragma unroll
    for (int r = 0; r < 4; ++r) {
      int rg = row0 + wrow * 64 + m * 16 + l4 * 4 + r;
      float psum = 0.f;
      #pragma unroll
      for (int n = 0; n < 4; ++n) {
        float v = fabsf(acc[m][n][r]);
        psum += v * lp[n];
        int colg = n0 + wcol * 64 + n * 16 + l15;
        size_t si = ((size_t)((rg >> 4) * 8 + j) * 16 + (rg & 15)) * ND + colg;
        int pk = __builtin_amdgcn_cvt_pk_fp8_f32(v, v, 0, false);
        Sout[si] = (unsigned char)(pk & 0xff);
      }
      psum += __shfl_xor(psum, 1);
      psum += __shfl_xor(psum, 2);
      psum += __shfl_xor(psum, 4);
      psum += __shfl_xor(psum, 8);
      if (l15 == 0) {
        int pidx = rg * 73 + 1 + j;
        atomicAdd(&phi[pidx], psum);
      }
    }
  }
}

// ==== layer-2: MX-fp8, round-13 structure (byte-identical; best measured) ====
__global__ __launch_bounds__(256, 2)
void gemm8_l2(const unsigned char* __restrict__ A,
              const unsigned char* __restrict__ BT,
              const float* __restrict__ lowpass,
              float* __restrict__ phi) {
  __shared__ __align__(16) unsigned char As[128 * 128];
  __shared__ __align__(16) unsigned char Bs[128 * 128];

  const int tid  = threadIdx.x;
  const int lane = tid & 63;
  const int w    = tid >> 6;          // 4 waves: 2M x 2N
  const int wrow = w >> 1, wcol = w & 1;
  const int l15  = lane & 15, l4 = lane >> 4;

  const int wg  = blockIdx.x;
  const int j   = wg & 7;             // XCD-pure (512 blocks all resident)
  const int idx = wg >> 3;            // 0..63
  const unsigned char* Bj = BT + (size_t)j * NNE;

  #pragma unroll 1
  for (int tt = 0; tt < 2; ++tt) {
    const int t = idx + tt * 64;      // 0..127
    const int mtile = t & 15, ntile = t >> 4;
    const int row0 = mtile * 128, n0 = ntile * 128;

    f32x4 acc[4][4] = {};

    #pragma unroll 1
    for (int k0 = 0; k0 < ND; k0 += 128) {
      __syncthreads();
      #pragma unroll
      for (int p = 0; p < 4; ++p) {
        int c = p * 256 + tid;
        int r = c >> 3;
        int s = (c & 7) ^ (r & 7);
        gload_lds16(A + (size_t)(row0 + r) * ND + k0 + (s << 4), As + c * 16);
      }
      #pragma unroll
      for (int p = 0; p < 4; ++p) {
        int c = p * 256 + tid;
        int r = c >> 3;
        int s = (c & 7) ^ (r & 7);
        gload_lds16(Bj + (size_t)(n0 + r) * ND + k0 + (s << 4), Bs + c * 16);
      }
      __syncthreads();

      i32x8 a[4], b[4];
      #pragma unroll
      for (int m = 0; m < 4; ++m)
        a[m] = dsr_frag8(As, wrow * 64 + m * 16 + l15, l4);
      #pragma unroll
      for (int n = 0; n < 4; ++n)
        b[n] = dsr_frag8(Bs, wcol * 64 + n * 16 + l15, l4);
      #pragma unroll
      for (int m = 0; m < 4; ++m)
        #pragma unroll
        for (int n = 0; n < 4; ++n)
          acc[m][n] = __builtin_amdgcn_mfma_scale_f32_16x16x128_f8f6f4(
              a[m], b[n], acc[m][n], 0, 0, 0, 0x7f7f7f7f, 0, 0x7f7f7f7f);
    }

    float lp[4];
    #pragma unroll
    for (int n = 0; n < 4; ++n)
      lp[n] = lowpass[n0 + wcol * 64 + n * 16 + l15];

    #pragma unroll
    for (int m = 0; m < 4; ++m) {
      #pragma unroll
      for (int r = 0; r < 4; ++r) {
        int rg = row0 + wrow * 64 + m * 16 + l4 * 4 + r;
        float psum = 0.f;
        #pragma unroll
        for (int n = 0; n < 4; ++n)
          psum += fabsf(acc[m][n][r]) * lp[n];
        psum += __shfl_xor(psum, 1);
        psum += __shfl_xor(psum, 2);
        psum += __shfl_xor(psum, 4);
        psum += __shfl_xor(psum, 8);
        if (l15 == 0) {
          int pidx = ((rg >> 7) * 16 + (rg & 15)) * 73 + 9 + ((rg >> 4) & 7) * 8 + j;
          atomicAdd(&phi[pidx], psum);
        }
      }
    }
  }
}

extern "C" void kernel_launch(void* const* d_in, const int* in_sizes, int n_in,
                              void* d_out, int out_size, void* d_ws, size_t ws_size,
                              hipStream_t stream) {
  (void)in_sizes; (void)n_in; (void)ws_size; (void)out_size;
  const float* x       = (const float*)d_in[0];
  const float* psi     = (const float*)d_in[1];
  const float* lowpass = (const float*)d_in[2];
  float* phi = (float*)d_out;

  unsigned char* x8    = (unsigned char*)d_ws;                        // 256 KB (fp8 x)
  unsigned char* psiT8 = (unsigned char*)((char*)d_ws + (1u << 20));  // 8 MB  (fp8 psi^T)
  unsigned char* S1f8  = (unsigned char*)((char*)d_ws + (10u << 20)); // 2 MB  (fp8 S1)

  // fused prep: 512 transpose tiles + 256 convert rows
  prep_kernel<<<768, 256, 0, stream>>>(psi, psiT8, x, lowpass, x8, phi);

  // layer 1: M=256 -> 128 blocks (all resident, j-pure), stores S1 fp8
  gemm8_l1<<<128, 256, 0, stream>>>(x8, psiT8, lowpass, S1f8, phi);

  // layer 2: 512 blocks (2/CU, all resident), 2 tiles/block
  gemm8_l2<<<512, 256, 0, stream>>>(S1f8, psiT8, lowpass, phi);
}

// Round 16
// 61.466 us; speedup vs baseline: 2.4453x; 1.0472x over previous
//
#include <hip/hip_runtime.h>

#define ND 1024
#define NNE (ND*ND)

typedef float f32x4 __attribute__((ext_vector_type(4)));
typedef int i32x4 __attribute__((ext_vector_type(4)));
typedef int i32x8 __attribute__((ext_vector_type(8)));

__device__ __forceinline__ void gload_lds16(const void* g, void* l) {
  __builtin_amdgcn_global_load_lds(
      (const __attribute__((address_space(1))) void*)g,
      (__attribute__((address_space(3))) void*)l, 16, 0, 0);
}

// ==== fused prep: 512 transpose blocks + 256 convert/phi0 blocks ====
__global__ __launch_bounds__(256)
void prep_kernel(const float* __restrict__ psi, unsigned char* __restrict__ out8,
                 const float* __restrict__ x, const float* __restrict__ lp,
                 unsigned char* __restrict__ x8, float* __restrict__ phi) {
  __shared__ __align__(16) unsigned char T[128 * 144];
  __shared__ float ws[4];
  const int blk = blockIdx.x;
  const int tid = threadIdx.x;

  if (blk >= 512) {
    int row = blk - 512;
    if (tid >= 1 && tid < 73) phi[row * 73 + tid] = 0.f;
    float4 v = reinterpret_cast<const float4*>(x + (size_t)row * ND)[tid];
    float4 l = reinterpret_cast<const float4*>(lp)[tid];
    int pk = __builtin_amdgcn_cvt_pk_fp8_f32(v.x, v.y, 0, false);
    pk = __builtin_amdgcn_cvt_pk_fp8_f32(v.z, v.w, pk, true);
    reinterpret_cast<unsigned int*>(x8 + (size_t)row * ND)[tid] = (unsigned int)pk;
    float s = v.x * l.x + v.y * l.y + v.z * l.z + v.w * l.w;
    #pragma unroll
    for (int off = 32; off; off >>= 1) s += __shfl_xor(s, off);
    if ((tid & 63) == 0) ws[tid >> 6] = s;
    __syncthreads();
    if (tid == 0) phi[row * 73] = ws[0] + ws[1] + ws[2] + ws[3];
    return;
  }

  const int j  = blk >> 6;
  const int t6 = blk & 63;
  const int tn = t6 >> 3, tm = t6 & 7;
  const int n0 = tn * 128, m0 = tm * 128;
  const float* src = psi + ((size_t)j << 20) + (size_t)n0 * ND + m0;

  const int rgrp = tid >> 5;
  const int c4   = (tid & 31) << 2;
  #pragma unroll
  for (int it = 0; it < 16; ++it) {
    int nl = it * 8 + rgrp;
    float4 v = *reinterpret_cast<const float4*>(src + (size_t)nl * ND + c4);
    int p01 = __builtin_amdgcn_cvt_pk_fp8_f32(v.x, v.y, 0, false);
    int p23 = __builtin_amdgcn_cvt_pk_fp8_f32(v.z, v.w, 0, false);
    T[(c4 + 0) * 144 + nl] = (unsigned char)(p01 & 0xff);
    T[(c4 + 1) * 144 + nl] = (unsigned char)((p01 >> 8) & 0xff);
    T[(c4 + 2) * 144 + nl] = (unsigned char)(p23 & 0xff);
    T[(c4 + 3) * 144 + nl] = (unsigned char)((p23 >> 8) & 0xff);
  }
  __syncthreads();

  unsigned char* dst = out8 + ((size_t)j << 20) + (size_t)m0 * ND + n0;
  const int mrow = tid >> 3;
  const int ch   = (tid & 7) << 4;
  #pragma unroll
  for (int it = 0; it < 4; ++it) {
    int ml = it * 32 + mrow;
    uint4 v = *reinterpret_cast<const uint4*>(&T[ml * 144 + ch]);
    *reinterpret_cast<uint4*>(dst + (size_t)ml * ND + ch) = v;
  }
}

// one 32B fp8 fragment: two swizzled ds_read_b128 combined (k-order preserved)
__device__ __forceinline__ i32x8 dsr_frag8(const unsigned char* base, int r, int l4) {
  int s0 = l4 * 2;
  i32x4 lo = *reinterpret_cast<const i32x4*>(base + r * 128 + ((s0 ^ (r & 7)) << 4));
  i32x4 hi = *reinterpret_cast<const i32x4*>(base + r * 128 + (((s0 + 1) ^ (r & 7)) << 4));
  return __builtin_shufflevector(lo, hi, 0, 1, 2, 3, 4, 5, 6, 7);
}

// stage one 128x128B fp8 tile-pair slice into As/Bs (8 x gload_lds16 / thread-group)
__device__ __forceinline__ void stage128(const unsigned char* __restrict__ A, int row0,
                                         const unsigned char* __restrict__ Bj, int n0,
                                         int k0, unsigned char* As, unsigned char* Bs,
                                         int tid) {
  #pragma unroll
  for (int p = 0; p < 4; ++p) {
    int c = p * 256 + tid;
    int r = c >> 3;
    int s = (c & 7) ^ (r & 7);
    gload_lds16(A + (size_t)(row0 + r) * ND + k0 + (s << 4), As + c * 16);
  }
  #pragma unroll
  for (int p = 0; p < 4; ++p) {
    int c = p * 256 + tid;
    int r = c >> 3;
    int s = (c & 7) ^ (r & 7);
    gload_lds16(Bj + (size_t)(n0 + r) * ND + k0 + (s << 4), Bs + c * 16);
  }
}

// compute one BK=128 K-step from staged buffers
__device__ __forceinline__ void compute128(const unsigned char* As, const unsigned char* Bs,
                                           f32x4 (&acc)[4][4],
                                           int wrow, int wcol, int l15, int l4) {
  i32x8 a[4], b[4];
  #pragma unroll
  for (int m = 0; m < 4; ++m)
    a[m] = dsr_frag8(As, wrow * 64 + m * 16 + l15, l4);
  #pragma unroll
  for (int n = 0; n < 4; ++n)
    b[n] = dsr_frag8(Bs, wcol * 64 + n * 16 + l15, l4);
  #pragma unroll
  for (int m = 0; m < 4; ++m)
    #pragma unroll
    for (int n = 0; n < 4; ++n)
      acc[m][n] = __builtin_amdgcn_mfma_scale_f32_16x16x128_f8f6f4(
          a[m], b[n], acc[m][n], 0, 0, 0, 0x7f7f7f7f, 0, 0x7f7f7f7f);
}

// ==== layer-1: MX-fp8, 128x128 tile, now LDS double-buffered ====
__global__ __launch_bounds__(256, 2)
void gemm8_l1(const unsigned char* __restrict__ A,
              const unsigned char* __restrict__ BT,
              const float* __restrict__ lowpass,
              unsigned char* __restrict__ Sout,
              float* __restrict__ phi) {
  __shared__ __align__(16) unsigned char As0[128 * 128];
  __shared__ __align__(16) unsigned char As1[128 * 128];
  __shared__ __align__(16) unsigned char Bs0[128 * 128];
  __shared__ __align__(16) unsigned char Bs1[128 * 128];

  const int tid  = threadIdx.x;
  const int lane = tid & 63;
  const int w    = tid >> 6;
  const int wrow = w >> 1, wcol = w & 1;
  const int l15  = lane & 15, l4 = lane >> 4;

  const int wg = blockIdx.x;
  const int j  = wg & 7;
  const int t  = wg >> 3;
  const int mtile = t & 1, ntile = t >> 1;
  const int row0 = mtile * 128, n0 = ntile * 128;
  const unsigned char* Bj = BT + (size_t)j * NNE;

  f32x4 acc[4][4] = {};

  stage128(A, row0, Bj, n0, 0, As0, Bs0, tid);
  __syncthreads();

  #pragma unroll 1
  for (int k0 = 0; k0 < ND; k0 += 128) {
    const int cur = (k0 >> 7) & 1;
    const unsigned char* Ac = cur ? As1 : As0;
    const unsigned char* Bc = cur ? Bs1 : Bs0;
    if (k0 + 128 < ND)
      stage128(A, row0, Bj, n0, k0 + 128, cur ? As0 : As1, cur ? Bs0 : Bs1, tid);
    compute128(Ac, Bc, acc, wrow, wcol, l15, l4);
    __syncthreads();
  }

  float lp[4];
  #pragma unroll
  for (int n = 0; n < 4; ++n)
    lp[n] = lowpass[n0 + wcol * 64 + n * 16 + l15];

  #pragma unroll
  for (int m = 0; m < 4; ++m) {
    #pragma unroll
    for (int r = 0; r < 4; ++r) {
      int rg = row0 + wrow * 64 + m * 16 + l4 * 4 + r;
      float psum = 0.f;
      #pragma unroll
      for (int n = 0; n < 4; ++n) {
        float v = fabsf(acc[m][n][r]);
        psum += v * lp[n];
        int colg = n0 + wcol * 64 + n * 16 + l15;
        size_t si = ((size_t)((rg >> 4) * 8 + j) * 16 + (rg & 15)) * ND + colg;
        int pk = __builtin_amdgcn_cvt_pk_fp8_f32(v, v, 0, false);
        Sout[si] = (unsigned char)(pk & 0xff);
      }
      psum += __shfl_xor(psum, 1);
      psum += __shfl_xor(psum, 2);
      psum += __shfl_xor(psum, 4);
      psum += __shfl_xor(psum, 8);
      if (l15 == 0) {
        int pidx = rg * 73 + 1 + j;
        atomicAdd(&phi[pidx], psum);
      }
    }
  }
}

// ==== layer-2: MX-fp8, round-13 geometry + LDS double-buffering ====
// 512 blocks (2/CU, all resident, j-pure), 2 output tiles per block.
__global__ __launch_bounds__(256, 2)
void gemm8_l2(const unsigned char* __restrict__ A,
              const unsigned char* __restrict__ BT,
              const float* __restrict__ lowpass,
              float* __restrict__ phi) {
  __shared__ __align__(16) unsigned char As0[128 * 128];
  __shared__ __align__(16) unsigned char As1[128 * 128];
  __shared__ __align__(16) unsigned char Bs0[128 * 128];
  __shared__ __align__(16) unsigned char Bs1[128 * 128];

  const int tid  = threadIdx.x;
  const int lane = tid & 63;
  const int w    = tid >> 6;
  const int wrow = w >> 1, wcol = w & 1;
  const int l15  = lane & 15, l4 = lane >> 4;

  const int wg  = blockIdx.x;
  const int j   = wg & 7;
  const int idx = wg >> 3;
  const unsigned char* Bj = BT + (size_t)j * NNE;

  #pragma unroll 1
  for (int tt = 0; tt < 2; ++tt) {
    const int t = idx + tt * 64;
    const int mtile = t & 15, ntile = t >> 4;
    const int row0 = mtile * 128, n0 = ntile * 128;

    f32x4 acc[4][4] = {};

    stage128(A, row0, Bj, n0, 0, As0, Bs0, tid);
    __syncthreads();

    #pragma unroll 1
    for (int k0 = 0; k0 < ND; k0 += 128) {
      const int cur = (k0 >> 7) & 1;
      const unsigned char* Ac = cur ? As1 : As0;
      const unsigned char* Bc = cur ? Bs1 : Bs0;
      if (k0 + 128 < ND)
        stage128(A, row0, Bj, n0, k0 + 128, cur ? As0 : As1, cur ? Bs0 : Bs1, tid);
      compute128(Ac, Bc, acc, wrow, wcol, l15, l4);
      __syncthreads();
    }

    float lp[4];
    #pragma unroll
    for (int n = 0; n < 4; ++n)
      lp[n] = lowpass[n0 + wcol * 64 + n * 16 + l15];

    #pragma unroll
    for (int m = 0; m < 4; ++m) {
      #pragma unroll
      for (int r = 0; r < 4; ++r) {
        int rg = row0 + wrow * 64 + m * 16 + l4 * 4 + r;
        float psum = 0.f;
        #pragma unroll
        for (int n = 0; n < 4; ++n)
          psum += fabsf(acc[m][n][r]) * lp[n];
        psum += __shfl_xor(psum, 1);
        psum += __shfl_xor(psum, 2);
        psum += __shfl_xor(psum, 4);
        psum += __shfl_xor(psum, 8);
        if (l15 == 0) {
          int pidx = ((rg >> 7) * 16 + (rg & 15)) * 73 + 9 + ((rg >> 4) & 7) * 8 + j;
          atomicAdd(&phi[pidx], psum);
        }
      }
    }
  }
}

extern "C" void kernel_launch(void* const* d_in, const int* in_sizes, int n_in,
                              void* d_out, int out_size, void* d_ws, size_t ws_size,
                              hipStream_t stream) {
  (void)in_sizes; (void)n_in; (void)ws_size; (void)out_size;
  const float* x       = (const float*)d_in[0];
  const float* psi     = (const float*)d_in[1];
  const float* lowpass = (const float*)d_in[2];
  float* phi = (float*)d_out;

  unsigned char* x8    = (unsigned char*)d_ws;                        // 256 KB (fp8 x)
  unsigned char* psiT8 = (unsigned char*)((char*)d_ws + (1u << 20));  // 8 MB  (fp8 psi^T)
  unsigned char* S1f8  = (unsigned char*)((char*)d_ws + (10u << 20)); // 2 MB  (fp8 S1)

  prep_kernel<<<768, 256, 0, stream>>>(psi, psiT8, x, lowpass, x8, phi);

  // layer 1: M=256 -> 128 blocks (all resident, j-pure), stores S1 fp8
  gemm8_l1<<<128, 256, 0, stream>>>(x8, psiT8, lowpass, S1f8, phi);

  // layer 2: 512 blocks (2/CU, all resident), 2 tiles/block, dbuf LDS
  gemm8_l2<<<512, 256, 0, stream>>>(S1f8, psiT8, lowpass, phi);
}